// Round 7
// baseline (156.190 us; speedup 1.0000x reference)
//
#include <hip/hip_runtime.h>

#define TT 140
#define BB 8192
#define HH 64
#define BT 16   // batch tile per block (MFMA N)
#define HS 72   // h-array stride in fp16 elems (144 B = 16B-aligned b128 frags)
#define FP ((TT - 1) & 1)   // parity of final step (=1)

typedef _Float16 half8 __attribute__((ext_vector_type(8)));
typedef _Float16 half4 __attribute__((ext_vector_type(4)));
typedef float    f32x4 __attribute__((ext_vector_type(4)));

#define MFMA16(a,b,c) __builtin_amdgcn_mfma_f32_16x16x32_f16(a, b, c, 0, 0, 0)

__device__ __forceinline__ float fast_tanh(float a) {
    float e = __builtin_amdgcn_exp2f(a * 2.88539008178f);
    return 1.0f - 2.0f * __builtin_amdgcn_rcpf(e + 1.0f);
}

// 16B-aligned LDS fragment load -> single ds_read_b128
__device__ __forceinline__ half8 ld_frag(const _Float16* p) {
    return *(const half8*)__builtin_assume_aligned(p, 16);
}

// load 8 f32 weights, convert to fp16
__device__ __forceinline__ half8 cvt_frag16(const float* p) {
    f32x4 wa = *(const f32x4*)p;
    f32x4 wb = *(const f32x4*)(p + 4);
    half8 h;
    #pragma unroll
    for (int j = 0; j < 8; ++j) h[j] = (_Float16)((j < 4) ? wa[j] : wb[j - 4]);
    return h;
}

// 8-wave role-split pipeline: waves 0-3 = layer0 quarters (step p), waves 4-7
// = layer1 quarters (step p-1). 512 blocks x 8 waves = 4096 waves = 16/CU =
// 4 waves/SIMD (round-5 measured 2/SIMD leaves VALUBusy pinned at 50% --
// exposed phase-chain latency; doubling TLP is the only occupancy lever left
// since batch tiles are capped at 512). Wave->SIMD round-robin pairs each
// light L0 wave with a heavy L1 wave per SIMD: balanced by construction.
__global__ __launch_bounds__(512, 4)
void rnn_kernel(const float* __restrict__ x,
                const float* __restrict__ h_state,
                const float* __restrict__ W_ih0,
                const float* __restrict__ W_hh0,
                const float* __restrict__ b_ih0,
                const float* __restrict__ b_hh0,
                const float* __restrict__ W_ih1,
                const float* __restrict__ W_hh1,
                const float* __restrict__ b_ih1,
                const float* __restrict__ b_hh1,
                const float* __restrict__ W_out,
                const float* __restrict__ b_out,
                float* __restrict__ out)
{
    __shared__ __align__(16) _Float16 h0f[2][BT * HS];
    __shared__ __align__(16) _Float16 h1f[2][BT * HS];
    __shared__ float xs[TT * 17];        // x staged [t][b]
    __shared__ float pps[TT * 68];       // projection partials [t][wl*17 + b]

    const int tid  = threadIdx.x;
    const int w    = tid >> 6;        // 0..7
    const int grp  = w >> 2;          // 0 = layer0 group, 1 = layer1 group
    const int wl   = w & 3;           // unit-quarter within layer (16*wl..)
    const int lane = tid & 63;
    const int col  = lane & 15;       // MFMA col (batch)
    const int q    = lane >> 4;       // quad
    const int b0   = blockIdx.x * BT;

    // ---- A-fragments (fp16), per role ----
    half8 A0[2], AI[2], AH[2];
    #pragma unroll
    for (int kt = 0; kt < 2; ++kt) {
        const int off = (16 * wl + col) * HH + 32 * kt + 8 * q;
        if (grp == 0) {
            A0[kt] = cvt_frag16(W_hh0 + off);
            AI[kt] = A0[kt]; AH[kt] = A0[kt];   // unused, keep defined
        } else {
            AI[kt] = cvt_frag16(W_ih1 + off);
            AH[kt] = cvt_frag16(W_hh1 + off);
            A0[kt] = AI[kt];
        }
    }
    // epilogue scalars: grp0: e0=bias0, e1=Wih0 ; grp1: e0=bias1, e1=Wout
    float e0[4], e1[4];
    #pragma unroll
    for (int r = 0; r < 4; ++r) {
        int j = 16 * wl + 4 * q + r;
        if (grp == 0) { e0[r] = b_ih0[j] + b_hh0[j]; e1[r] = W_ih0[j]; }
        else          { e0[r] = b_ih1[j] + b_hh1[j]; e1[r] = W_out[j]; }
    }
    const float bout = b_out[0];

    // ---- stage x[b0..b0+15][0..139] into LDS [t][b] (512 threads) ----
    for (int c = 0; c < (TT * BT + 511) / 512; ++c) {
        int i = c * 512 + tid;
        if (i < TT * BT) {
            int t = i >> 4, b = i & 15;
            xs[t * 17 + b] = x[(size_t)(b0 + b) * TT + t];
        }
    }
    // ---- init hidden state ([2,B,H]) into parity-1 buffers (step "-1") ----
    #pragma unroll
    for (int c = 0; c < (BT * HH) / 512; ++c) {
        int i = c * 512 + tid;
        int b = i >> 6, u = i & 63;
        h0f[1][b * HS + u] = (_Float16)h_state[(size_t)(b0 + b) * HH + u];
        h1f[1][b * HS + u] = (_Float16)h_state[(size_t)BB * HH + (size_t)(b0 + b) * HH + u];
    }
    __syncthreads();

    // ---- pipelined phase loop: p=0..TT ----
    for (int p = 0; p <= TT; ++p) {
        if (grp == 0) {
            if (p < TT) {
                // layer0 step p: read h0(p-1) parity (p+1)&1, write parity p&1
                const int rb = (p + 1) & 1, wb = p & 1;
                half8 H0a = ld_frag(&h0f[rb][col * HS + 8 * q]);
                half8 H0b = ld_frag(&h0f[rb][col * HS + 32 + 8 * q]);
                float xt  = xs[p * 17 + col];
                f32x4 c = {0.f, 0.f, 0.f, 0.f};
                c = MFMA16(A0[0], H0a, c);
                c = MFMA16(A0[1], H0b, c);
                half4 h4;
                #pragma unroll
                for (int r = 0; r < 4; ++r) {
                    float pre = c[r] + e0[r] + e1[r] * xt;
                    h4[r] = (_Float16)fast_tanh(pre);
                }
                *(half4*)(&h0f[wb][col * HS + 16 * wl + 4 * q]) = h4;
            }
        } else {
            if (p >= 1) {
                // layer1 step s=p-1: read h0n(s) parity s&1 (written by grp0
                // last phase), h1(s-1) parity (s+1)&1; write h1(s) parity s&1
                const int s   = p - 1;
                const int rb0 = s & 1, rb1 = (s + 1) & 1, wb1 = s & 1;
                half8 H1a = ld_frag(&h1f[rb1][col * HS + 8 * q]);
                half8 H1b = ld_frag(&h1f[rb1][col * HS + 32 + 8 * q]);
                half8 H0a = ld_frag(&h0f[rb0][col * HS + 8 * q]);
                half8 H0b = ld_frag(&h0f[rb0][col * HS + 32 + 8 * q]);
                f32x4 ci = {0.f, 0.f, 0.f, 0.f}, ch = {0.f, 0.f, 0.f, 0.f};
                ch = MFMA16(AH[0], H1a, ch);
                ch = MFMA16(AH[1], H1b, ch);
                ci = MFMA16(AI[0], H0a, ci);
                ci = MFMA16(AI[1], H0b, ci);
                f32x4 a = ci + ch;
                float pr = 0.f;
                half4 h4;
                #pragma unroll
                for (int r = 0; r < 4; ++r) {
                    float pre = a[r] + e0[r];
                    float hn  = fast_tanh(pre);
                    pr += hn * e1[r];
                    h4[r] = (_Float16)hn;
                }
                *(half4*)(&h1f[wb1][col * HS + 16 * wl + 4 * q]) = h4;
                pr += __shfl_xor(pr, 16, 64);
                pr += __shfl_xor(pr, 32, 64);
                if (lane < 16) pps[s * 68 + wl * 17 + lane] = pr;
            }
        }
        __syncthreads();
    }

    // ---- epilogue: fold 4 quarter-partials + store y; wave w -> batches w, 8+w ----
    #pragma unroll
    for (int bq = 0; bq < 2; ++bq) {
        int b = 8 * bq + w;
        #pragma unroll
        for (int c = 0; c < 3; ++c) {
            int t = c * 64 + lane;
            if (t < TT)
                out[(size_t)(b0 + b) * TT + t] =
                    pps[t * 68 + b] + pps[t * 68 + 17 + b]
                  + pps[t * 68 + 34 + b] + pps[t * 68 + 51 + b] + bout;
        }
    }
    // ---- h_final: [2,B,H] appended after out[B*T]; final parity FP ----
    const size_t OFF = (size_t)BB * TT;
    #pragma unroll
    for (int c = 0; c < (BT * HH) / 512; ++c) {
        int i = c * 512 + tid;
        int b = i >> 6, u = i & 63;
        out[OFF + (size_t)(b0 + b) * HH + u] = (float)h0f[FP][b * HS + u];
        out[OFF + (size_t)BB * HH + (size_t)(b0 + b) * HH + u] = (float)h1f[FP][b * HS + u];
    }
}

extern "C" void kernel_launch(void* const* d_in, const int* in_sizes, int n_in,
                              void* d_out, int out_size, void* d_ws, size_t ws_size,
                              hipStream_t stream) {
    const float* x      = (const float*)d_in[0];
    const float* hst    = (const float*)d_in[1];
    const float* W_ih0  = (const float*)d_in[2];
    const float* W_hh0  = (const float*)d_in[3];
    const float* b_ih0  = (const float*)d_in[4];
    const float* b_hh0  = (const float*)d_in[5];
    const float* W_ih1  = (const float*)d_in[6];
    const float* W_hh1  = (const float*)d_in[7];
    const float* b_ih1  = (const float*)d_in[8];
    const float* b_hh1  = (const float*)d_in[9];
    const float* W_out  = (const float*)d_in[10];
    const float* b_outp = (const float*)d_in[11];
    float* out = (float*)d_out;

    dim3 grid(BB / BT);   // 512 blocks x 8 waves = 4096 waves = 16/CU (4/SIMD)
    dim3 block(512);
    rnn_kernel<<<grid, block, 0, stream>>>(x, hst, W_ih0, W_hh0, b_ih0, b_hh0,
                                           W_ih1, W_hh1, b_ih1, b_hh1,
                                           W_out, b_outp, out);
}